// Round 6
// baseline (247.887 us; speedup 1.0000x reference)
//
#include <hip/hip_runtime.h>
#include <hip/hip_bf16.h>
#include <stdint.h>

typedef float  f32x4  __attribute__((ext_vector_type(4)));
typedef __bf16 bf16x8 __attribute__((ext_vector_type(8)));
typedef unsigned short us4 __attribute__((ext_vector_type(4)));

#define NDIM 4096
#define DDIM 512

__device__ __forceinline__ unsigned short f2bf(float f) {
    union { float f; uint32_t u; } v; v.f = f;
    uint32_t u = v.u;
    u += 0x7FFFu + ((u >> 16) & 1u);   // round-to-nearest-even
    return (unsigned short)(u >> 16);
}

// Fused prep (block-range dispatch):
//   [0, 16384)      : A fp32 -> bf16 with +I      (4096x4096, float4/thread)
//   [16384, 18432)  : X fp32 -> bf16              (4096x512)
//   [18432, 18688)  : W fp32 -> bf16              (512x512)
//   [18688, 18704)  : ds[i] = rsqrt(A[i,i]+1)
//   [18704, 20752)  : zero Ctmp (8 MB fp32 accumulator)
__global__ void prep_kernel(const float* __restrict__ A, const float* __restrict__ X,
                            const float* __restrict__ W,
                            unsigned short* __restrict__ A2, unsigned short* __restrict__ Xb,
                            unsigned short* __restrict__ Wb, float* __restrict__ ds,
                            float* __restrict__ Ctmp) {
    const int b = blockIdx.x, tid = threadIdx.x;
    if (b < 16384) {
        int i = b * 256 + tid;          // float4 index into A
        int e = i << 2;
        int row = e >> 12, col = e & 4095;
        f32x4 v = ((const f32x4*)A)[i];
        int d = row - col;
        if (d >= 0 && d < 4) v[d] += 1.0f;
        us4 o; o.x = f2bf(v.x); o.y = f2bf(v.y); o.z = f2bf(v.z); o.w = f2bf(v.w);
        ((us4*)A2)[i] = o;
    } else if (b < 18432) {
        int i = (b - 16384) * 256 + tid;
        f32x4 v = ((const f32x4*)X)[i];
        us4 o; o.x = f2bf(v.x); o.y = f2bf(v.y); o.z = f2bf(v.z); o.w = f2bf(v.w);
        ((us4*)Xb)[i] = o;
    } else if (b < 18688) {
        int i = (b - 18432) * 256 + tid;
        f32x4 v = ((const f32x4*)W)[i];
        us4 o; o.x = f2bf(v.x); o.y = f2bf(v.y); o.z = f2bf(v.z); o.w = f2bf(v.w);
        ((us4*)Wb)[i] = o;
    } else if (b < 18704) {
        int i = (b - 18688) * 256 + tid;
        if (i < NDIM) ds[i] = rsqrtf(A[(size_t)i * (NDIM + 1)] + 1.0f);
    } else {
        int i = (b - 18704) * 256 + tid;
        ((f32x4*)Ctmp)[i] = (f32x4)0.0f;
    }
}

// C = A @ B^T.  A: [M x K] bf16 row-major, B: [Nr x K] bf16 row-major.
// BM=BN=128, BK=64, 4 waves (2x2), wave-tile 64x64 (4x4 MFMAs of 16x16x32).
// Single-buffered (r3 evidence: the staging pipe sustains ~12 TB/s when >=4
// blocks/CU hide the per-block barrier drain; dbuf is compiler-defeated).
// __launch_bounds__(256,4) + z=8 k-split -> 1024 blocks = 4 blocks/CU:
// r4's staging efficiency (128 FLOP/staged byte) x r3's latency hiding.
// Grid: (x, y, z); z = K-chunk of size kc.
//   SWAP=0: x = m-tile, y = n-tile.  SWAP=1: x = n-tile, y = m-tile.
//   grid-x walks the LARGE streamed matrix (XCD pinning: linear id % 8 = x % 8;
//   32 and 128 are both divisible by 8 so y,z don't perturb the XCD).
// MODE 0: store bf16 TRANSPOSED (C_t[n][m], ldc = M), single k-chunk.
// MODE 3: unsafeAtomicAdd fp32 into row-major C [M x ldc] (k-split partials).
template <int MODE, int SWAP>
__global__ __launch_bounds__(256, 4) void gemm_bt(
    const unsigned short* __restrict__ A,
    const unsigned short* __restrict__ B,
    void* __restrict__ C,
    int K, int kc, int ldc)
{
    __shared__ unsigned short lsA[128 * 64];  // 16 KB, rows of 128 B, XOR-16B swizzled
    __shared__ unsigned short lsB[128 * 64];  // 16 KB

    const int tid  = threadIdx.x;
    const int wid  = tid >> 6;
    const int lane = tid & 63;
    const int m0 = (SWAP ? blockIdx.y : blockIdx.x) * 128;
    const int n0 = (SWAP ? blockIdx.x : blockIdx.y) * 128;
    const int kbase = blockIdx.z * kc;
    const int wm = (wid & 1) * 64;
    const int wn = (wid >> 1) * 64;

    // staging: instr t covers LDS rows t*8+(l>>3), phys 16B-col (l&7);
    // phys col holds logical col ((l&7)^(l>>3)) — XOR applied on global side.
    const int lrow = lane >> 3;
    const int lcsw = ((lane & 7) ^ lrow) * 16;

    f32x4 acc[4][4];
    #pragma unroll
    for (int i = 0; i < 4; i++)
        #pragma unroll
        for (int j = 0; j < 4; j++) acc[i][j] = (f32x4)0.0f;

    // instr t = wid*4+i -> global rows m0 + wid*32 + i*8 + lrow
    const char* gA = (const char*)A + ((size_t)(m0 + wid * 32 + lrow) * K) * 2 + lcsw;
    const char* gB = (const char*)B + ((size_t)(n0 + wid * 32 + lrow) * K) * 2 + lcsw;
    const size_t rowstep = (size_t)8 * K * 2;

    for (int k0 = kbase; k0 < kbase + kc; k0 += 64) {
        const size_t kb = (size_t)k0 * 2;
        #pragma unroll
        for (int i = 0; i < 4; i++) {
            __builtin_amdgcn_global_load_lds(
                (const __attribute__((address_space(1))) void*)(gA + kb + (size_t)i * rowstep),
                (__attribute__((address_space(3))) void*)(&lsA[(wid * 4 + i) * 512]),
                16, 0, 0);
            __builtin_amdgcn_global_load_lds(
                (const __attribute__((address_space(1))) void*)(gB + kb + (size_t)i * rowstep),
                (__attribute__((address_space(3))) void*)(&lsB[(wid * 4 + i) * 512]),
                16, 0, 0);
        }
        __syncthreads();

        #pragma unroll
        for (int ks = 0; ks < 2; ks++) {
            const int kboff = ks * 64 + (lane >> 4) * 16;  // byte offset in 128B row
            bf16x8 bfrag[4], afrag[4];
            #pragma unroll
            for (int nt = 0; nt < 4; nt++) {
                int r = wn + nt * 16 + (lane & 15);
                bfrag[nt] = *(const bf16x8*)((const char*)lsB + r * 128 + (kboff ^ ((r & 7) * 16)));
            }
            #pragma unroll
            for (int mt = 0; mt < 4; mt++) {
                int r = wm + mt * 16 + (lane & 15);
                afrag[mt] = *(const bf16x8*)((const char*)lsA + r * 128 + (kboff ^ ((r & 7) * 16)));
            }
            #pragma unroll
            for (int mt = 0; mt < 4; mt++)
                #pragma unroll
                for (int nt = 0; nt < 4; nt++)
                    acc[mt][nt] = __builtin_amdgcn_mfma_f32_16x16x32_bf16(
                        afrag[mt], bfrag[nt], acc[mt][nt], 0, 0, 0);
        }
        __syncthreads();
    }

    // epilogue.  C/D layout: col = lane&15, row = (lane>>4)*4 + reg
    const int col  = lane & 15;
    const int quad = lane >> 4;
    #pragma unroll
    for (int mt = 0; mt < 4; mt++) {
        const int gm0 = m0 + wm + mt * 16 + quad * 4;   // 4 consecutive rows
        #pragma unroll
        for (int nt = 0; nt < 4; nt++) {
            const int gn = n0 + wn + nt * 16 + col;
            f32x4 v = acc[mt][nt];
            if (MODE == 0) {
                us4 o;
                o.x = f2bf(v.x); o.y = f2bf(v.y); o.z = f2bf(v.z); o.w = f2bf(v.w);
                *(us4*)((unsigned short*)C + (size_t)gn * ldc + gm0) = o;
            } else {
                float* o = (float*)C + (size_t)gm0 * ldc + gn;
                unsafeAtomicAdd(&o[0],               v.x);
                unsafeAtomicAdd(&o[ldc],             v.y);
                unsafeAtomicAdd(&o[2 * (size_t)ldc], v.z);
                unsafeAtomicAdd(&o[3 * (size_t)ldc], v.w);
            }
        }
    }
}

// T2[j][i] = bf16(ds[i] * Ctmp[j][i]); re-zero Ctmp for GEMM3's accumulation.
// Ctmp/T2: [512 x 4096], elementwise, f32x4 per thread.
__global__ void ep2_kernel(float* __restrict__ Ctmp, const float* __restrict__ ds,
                           unsigned short* __restrict__ T2) {
    int t = blockIdx.x * 256 + threadIdx.x;
    int e = t << 2;
    int i = e & 4095;                  // column index
    f32x4 v = ((f32x4*)Ctmp)[t];
    f32x4 d = *(const f32x4*)(ds + i);
    us4 o;
    o.x = f2bf(v.x * d.x); o.y = f2bf(v.y * d.y);
    o.z = f2bf(v.z * d.z); o.w = f2bf(v.w * d.w);
    ((us4*)T2)[t] = o;
    ((f32x4*)Ctmp)[t] = (f32x4)0.0f;
}

// out[i][j] = relu(ds[i] * Ctmp[i][j]).  Ctmp/out: [4096 x 512] fp32.
__global__ void ep3_kernel(const float* __restrict__ Ctmp, const float* __restrict__ ds,
                           float* __restrict__ out) {
    int t = blockIdx.x * 256 + threadIdx.x;
    int e = t << 2;
    int i = e >> 9;                    // row index
    float s = ds[i];
    f32x4 v = ((const f32x4*)Ctmp)[t];
    f32x4 o;
    o.x = fmaxf(v.x * s, 0.0f); o.y = fmaxf(v.y * s, 0.0f);
    o.z = fmaxf(v.z * s, 0.0f); o.w = fmaxf(v.w * s, 0.0f);
    ((f32x4*)out)[t] = o;
}

extern "C" void kernel_launch(void* const* d_in, const int* in_sizes, int n_in,
                              void* d_out, int out_size, void* d_ws, size_t ws_size,
                              hipStream_t stream) {
    const float* X = (const float*)d_in[0];   // [4096 x 512]
    const float* A = (const float*)d_in[1];   // [4096 x 4096]
    const float* W = (const float*)d_in[2];   // [512 x 512]

    char* ws = (char*)d_ws;
    float*          dsc  = (float*)ws;                           // 16 KB
    unsigned short* A2   = (unsigned short*)(ws + 16384);        // 32 MB   bf16 A+I
    unsigned short* Xb   = (unsigned short*)(ws + 33570816u);    // 4 MB
    unsigned short* Wb   = (unsigned short*)(ws + 37765120u);    // 512 KB
    unsigned short* Yt   = (unsigned short*)(ws + 38289408u);    // 4 MB    (X@W^T)^T  [512][4096]
    unsigned short* T2   = (unsigned short*)(ws + 42483712u);    // 4 MB    ds*(A2@Y) transposed [512][4096]
    float*          Ctmp = (float*)(ws + 46678016u);             // 8 MB    fp32 k-split accumulator

    prep_kernel<<<20752, 256, 0, stream>>>(A, X, W, A2, Xb, Wb, dsc, Ctmp);

    // Yt = (Xb @ Wb^T)^T  [512][4096] bf16.  M=4096 (32 m-tiles), N=512 (4 n-tiles).
    gemm_bt<0, 0><<<dim3(32, 4, 1), 256, 0, stream>>>(Xb, Wb, Yt, 512, 512, 4096);
    // Ctmp[512x4096] += Yt @ A2^T  (M=512: 4 m-tiles; N=4096: 32 n-tiles = grid-x; K split x8).
    gemm_bt<3, 1><<<dim3(32, 4, 8), 256, 0, stream>>>(Yt, A2, Ctmp, 4096, 512, 4096);
    // T2 = bf16(ds_col * Ctmp); re-zero Ctmp.
    ep2_kernel<<<2048, 256, 0, stream>>>(Ctmp, dsc, T2);
    // Ctmp[4096x512] += A2 @ T2^T  (M=4096: 32 m-tiles = grid-x; N=512: 4 n-tiles; K split x8).
    gemm_bt<3, 0><<<dim3(32, 4, 8), 256, 0, stream>>>(A2, T2, Ctmp, 4096, 512, 512);
    // out = relu(ds_row * Ctmp)  [4096 x 512] fp32.
    ep3_kernel<<<2048, 256, 0, stream>>>(Ctmp, dsc, (float*)d_out);
}

// Round 7
// 191.615 us; speedup vs baseline: 1.2937x; 1.2937x over previous
//
#include <hip/hip_runtime.h>
#include <hip/hip_bf16.h>
#include <stdint.h>

typedef float  f32x4  __attribute__((ext_vector_type(4)));
typedef __bf16 bf16x8 __attribute__((ext_vector_type(8)));
typedef unsigned short us4 __attribute__((ext_vector_type(4)));

#define NDIM 4096
#define DDIM 512
#define PSTRIDE 2097152   // 512*4096 = 4096*512 floats per split-K partial

__device__ __forceinline__ unsigned short f2bf(float f) {
    union { float f; uint32_t u; } v; v.f = f;
    uint32_t u = v.u;
    u += 0x7FFFu + ((u >> 16) & 1u);   // round-to-nearest-even
    return (unsigned short)(u >> 16);
}

// Fused prep (block-range dispatch):
//   [0, 16384)      : A fp32 -> bf16 with +I      (4096x4096, float4/thread)
//   [16384, 18432)  : X fp32 -> bf16              (4096x512)
//   [18432, 18688)  : W fp32 -> bf16              (512x512)
//   [18688, 18704)  : ds[i] = rsqrt(A[i,i]+1)
__global__ void prep_kernel(const float* __restrict__ A, const float* __restrict__ X,
                            const float* __restrict__ W,
                            unsigned short* __restrict__ A2, unsigned short* __restrict__ Xb,
                            unsigned short* __restrict__ Wb, float* __restrict__ ds) {
    const int b = blockIdx.x, tid = threadIdx.x;
    if (b < 16384) {
        int i = b * 256 + tid;          // float4 index into A
        int e = i << 2;
        int row = e >> 12, col = e & 4095;
        f32x4 v = ((const f32x4*)A)[i];
        int d = row - col;
        if (d >= 0 && d < 4) v[d] += 1.0f;
        us4 o; o.x = f2bf(v.x); o.y = f2bf(v.y); o.z = f2bf(v.z); o.w = f2bf(v.w);
        ((us4*)A2)[i] = o;
    } else if (b < 18432) {
        int i = (b - 16384) * 256 + tid;
        f32x4 v = ((const f32x4*)X)[i];
        us4 o; o.x = f2bf(v.x); o.y = f2bf(v.y); o.z = f2bf(v.z); o.w = f2bf(v.w);
        ((us4*)Xb)[i] = o;
    } else if (b < 18688) {
        int i = (b - 18432) * 256 + tid;
        f32x4 v = ((const f32x4*)W)[i];
        us4 o; o.x = f2bf(v.x); o.y = f2bf(v.y); o.z = f2bf(v.z); o.w = f2bf(v.w);
        ((us4*)Wb)[i] = o;
    } else {
        int i = (b - 18688) * 256 + tid;
        if (i < NDIM) ds[i] = rsqrtf(A[(size_t)i * (NDIM + 1)] + 1.0f);
    }
}

// C = A @ B^T.  A: [M x K] bf16 row-major, B: [Nr x K] bf16 row-major.
// BM=BN=128, BK=64, 4 waves (2x2), wave-tile 64x64 (4x4 MFMAs of 16x16x32).
// EXACT m97 staging: LINEAR lane->address (no XOR) so each global_load_lds
// coalesces into 8 x 128B transactions (the r1-r5 global-side XOR permuted
// lanes within the 128B segment -> ~8x VMEM transaction inflation; LDS bank
// conflicts from linear layout are tolerated, m97-style: LDS is not the wall).
// NO atomics: split-K partials go to separate fp32 buffers (plain stores),
// reduced in the elementwise epilogue kernels.
// Grid: (x, y, z); z = K-chunk of size kc.
//   SWAP=0: x = m-tile, y = n-tile.  SWAP=1: x = n-tile, y = m-tile.
//   grid-x walks the LARGE streamed matrix (XCD pinning: linear id % 8 = x % 8).
// MODE 0: store bf16 TRANSPOSED (C_t[n][m], ldc = M), single k-chunk.
// MODE 2: plain fp32 stores into partial buffer C + z*PSTRIDE, row-major [M x ldc].
template <int MODE, int SWAP>
__global__ __launch_bounds__(256, 4) void gemm_bt(
    const unsigned short* __restrict__ A,
    const unsigned short* __restrict__ B,
    void* __restrict__ C,
    int K, int kc, int ldc)
{
    __shared__ unsigned short lsA[128 * 64];  // 16 KB, rows of 128 B, linear
    __shared__ unsigned short lsB[128 * 64];  // 16 KB

    const int tid  = threadIdx.x;
    const int wid  = tid >> 6;
    const int lane = tid & 63;
    const int m0 = (SWAP ? blockIdx.y : blockIdx.x) * 128;
    const int n0 = (SWAP ? blockIdx.x : blockIdx.y) * 128;
    const int kbase = blockIdx.z * kc;
    const int wm = (wid & 1) * 64;
    const int wn = (wid >> 1) * 64;

    // staging: instr t covers LDS rows t*8+(l>>3), 16B col (l&7) — LINEAR.
    const int lrow = lane >> 3;
    const int lcs  = (lane & 7) * 16;

    f32x4 acc[4][4];
    #pragma unroll
    for (int i = 0; i < 4; i++)
        #pragma unroll
        for (int j = 0; j < 4; j++) acc[i][j] = (f32x4)0.0f;

    // instr t = wid*4+i -> global rows m0 + wid*32 + i*8 + lrow
    const char* gA = (const char*)A + ((size_t)(m0 + wid * 32 + lrow) * K) * 2 + lcs;
    const char* gB = (const char*)B + ((size_t)(n0 + wid * 32 + lrow) * K) * 2 + lcs;
    const size_t rowstep = (size_t)8 * K * 2;

    for (int k0 = kbase; k0 < kbase + kc; k0 += 64) {
        const size_t kb = (size_t)k0 * 2;
        #pragma unroll
        for (int i = 0; i < 4; i++) {
            __builtin_amdgcn_global_load_lds(
                (const __attribute__((address_space(1))) void*)(gA + kb + (size_t)i * rowstep),
                (__attribute__((address_space(3))) void*)(&lsA[(wid * 4 + i) * 512]),
                16, 0, 0);
            __builtin_amdgcn_global_load_lds(
                (const __attribute__((address_space(1))) void*)(gB + kb + (size_t)i * rowstep),
                (__attribute__((address_space(3))) void*)(&lsB[(wid * 4 + i) * 512]),
                16, 0, 0);
        }
        __syncthreads();

        #pragma unroll
        for (int ks = 0; ks < 2; ks++) {
            const int kboff = ks * 64 + (lane >> 4) * 16;  // byte offset in 128B row
            bf16x8 bfrag[4], afrag[4];
            #pragma unroll
            for (int nt = 0; nt < 4; nt++) {
                int r = wn + nt * 16 + (lane & 15);
                bfrag[nt] = *(const bf16x8*)((const char*)lsB + r * 128 + kboff);
            }
            #pragma unroll
            for (int mt = 0; mt < 4; mt++) {
                int r = wm + mt * 16 + (lane & 15);
                afrag[mt] = *(const bf16x8*)((const char*)lsA + r * 128 + kboff);
            }
            #pragma unroll
            for (int mt = 0; mt < 4; mt++)
                #pragma unroll
                for (int nt = 0; nt < 4; nt++)
                    acc[mt][nt] = __builtin_amdgcn_mfma_f32_16x16x32_bf16(
                        afrag[mt], bfrag[nt], acc[mt][nt], 0, 0, 0);
        }
        __syncthreads();
    }

    // epilogue.  C/D layout: col = lane&15, row = (lane>>4)*4 + reg
    const int col  = lane & 15;
    const int quad = lane >> 4;
    #pragma unroll
    for (int mt = 0; mt < 4; mt++) {
        const int gm0 = m0 + wm + mt * 16 + quad * 4;   // 4 consecutive rows
        #pragma unroll
        for (int nt = 0; nt < 4; nt++) {
            const int gn = n0 + wn + nt * 16 + col;
            f32x4 v = acc[mt][nt];
            if (MODE == 0) {
                us4 o;
                o.x = f2bf(v.x); o.y = f2bf(v.y); o.z = f2bf(v.z); o.w = f2bf(v.w);
                *(us4*)((unsigned short*)C + (size_t)gn * ldc + gm0) = o;
            } else {
                float* o = (float*)C + (size_t)blockIdx.z * PSTRIDE + (size_t)gm0 * ldc + gn;
                o[0]               = v.x;
                o[ldc]             = v.y;
                o[2 * (size_t)ldc] = v.z;
                o[3 * (size_t)ldc] = v.w;
            }
        }
    }
}

// T2[j][i] = bf16(ds[i] * sum_z P[z][j][i]).  P: 4 partials [512 x 4096] fp32.
__global__ void ep2_kernel(const float* __restrict__ P, const float* __restrict__ ds,
                           unsigned short* __restrict__ T2) {
    int t = blockIdx.x * 256 + threadIdx.x;
    int e = t << 2;
    int i = e & 4095;                  // column index
    f32x4 v = ((const f32x4*)P)[t];
    v += ((const f32x4*)(P + PSTRIDE))[t];
    v += ((const f32x4*)(P + 2 * PSTRIDE))[t];
    v += ((const f32x4*)(P + 3 * PSTRIDE))[t];
    f32x4 d = *(const f32x4*)(ds + i);
    us4 o;
    o.x = f2bf(v.x * d.x); o.y = f2bf(v.y * d.y);
    o.z = f2bf(v.z * d.z); o.w = f2bf(v.w * d.w);
    ((us4*)T2)[t] = o;
}

// out[i][j] = relu(ds[i] * sum_z Q[z][i][j]).  Q: 4 partials [4096 x 512] fp32.
__global__ void ep3_kernel(const float* __restrict__ Q, const float* __restrict__ ds,
                           float* __restrict__ out) {
    int t = blockIdx.x * 256 + threadIdx.x;
    int e = t << 2;
    int i = e >> 9;                    // row index
    float s = ds[i];
    f32x4 v = ((const f32x4*)Q)[t];
    v += ((const f32x4*)(Q + PSTRIDE))[t];
    v += ((const f32x4*)(Q + 2 * PSTRIDE))[t];
    v += ((const f32x4*)(Q + 3 * PSTRIDE))[t];
    f32x4 o;
    o.x = fmaxf(v.x * s, 0.0f); o.y = fmaxf(v.y * s, 0.0f);
    o.z = fmaxf(v.z * s, 0.0f); o.w = fmaxf(v.w * s, 0.0f);
    ((f32x4*)out)[t] = o;
}

extern "C" void kernel_launch(void* const* d_in, const int* in_sizes, int n_in,
                              void* d_out, int out_size, void* d_ws, size_t ws_size,
                              hipStream_t stream) {
    const float* X = (const float*)d_in[0];   // [4096 x 512]
    const float* A = (const float*)d_in[1];   // [4096 x 4096]
    const float* W = (const float*)d_in[2];   // [512 x 512]

    char* ws = (char*)d_ws;
    float*          dsc  = (float*)ws;                           // 16 KB
    unsigned short* A2   = (unsigned short*)(ws + 16384);        // 32 MB   bf16 A+I
    unsigned short* Xb   = (unsigned short*)(ws + 33570816u);    // 4 MB
    unsigned short* Wb   = (unsigned short*)(ws + 37765120u);    // 512 KB
    unsigned short* Yt   = (unsigned short*)(ws + 38289408u);    // 4 MB    (X@W^T)^T  [512][4096]
    unsigned short* T2   = (unsigned short*)(ws + 42483712u);    // 4 MB    ds*(A2@Y) transposed [512][4096]
    float*          Part = (float*)(ws + 46678016u);             // 32 MB   4 x fp32 split-K partials

    prep_kernel<<<18704, 256, 0, stream>>>(A, X, W, A2, Xb, Wb, dsc);

    // Yt = (Xb @ Wb^T)^T  [512][4096] bf16.  M=4096 (32 m-tiles = grid-x), N=512 (4 n-tiles).
    gemm_bt<0, 0><<<dim3(32, 4, 1), 256, 0, stream>>>(Xb, Wb, Yt, 512, 512, 4096);
    // Part[z][512][4096] = Yt @ A2^T partials (M=512: 4 m-tiles=y; N=4096: 32 n-tiles=x; z=4).
    gemm_bt<2, 1><<<dim3(32, 4, 4), 256, 0, stream>>>(Yt, A2, Part, 4096, 1024, 4096);
    // T2 = bf16(ds_col * sum_z Part[z]).
    ep2_kernel<<<2048, 256, 0, stream>>>(Part, dsc, T2);
    // Part[z][4096][512] = A2 @ T2^T partials (M=4096: 32 m-tiles=x; N=512: 4 n-tiles=y; z=4).
    gemm_bt<2, 0><<<dim3(32, 4, 4), 256, 0, stream>>>(A2, T2, Part, 4096, 1024, 512);
    // out = relu(ds_row * sum_z Part[z])  [4096 x 512] fp32.
    ep3_kernel<<<2048, 256, 0, stream>>>(Part, dsc, (float*)d_out);
}